// Round 6
// baseline (365.224 us; speedup 1.0000x reference)
//
#include <hip/hip_runtime.h>

// SelfAttentionBlock: x[8,2048,512]; Wq/Wk/Wv [512,512]; bq/bk/bv [512].
// out[8,2048,1024] = concat(x, causal_softmax(QK^T/sqrt(512)) @ V).
// v6: attn with 512-thread blocks (8 waves = 2/SIMD): key-split S phase +
// cross-wave softmax via LDS, 8-way d-split PV. All reg indices compile-time.

#define DEV __device__ __forceinline__

typedef unsigned short u16;
typedef unsigned int u32;
typedef __attribute__((ext_vector_type(8))) short short8;   // 8 bf16 = 4 VGPRs
typedef __attribute__((ext_vector_type(4))) float float4v;  // MFMA C/D frag

DEV u16 f2bf(float f) {
    u32 u = __float_as_uint(f);
    return (u16)((u + 0x7FFFu + ((u >> 16) & 1u)) >> 16);
}
DEV float bf2f(u16 h) { return __uint_as_float(((u32)h) << 16); }

DEV float4v mfma16(short8 a, short8 b, float4v c) {
    return __builtin_amdgcn_mfma_f32_16x16x32_bf16(a, b, c, 0, 0, 0);
}

// async global->LDS, 16B per lane; LDS dest = wave-uniform base + lane*16
#define GLD16(gptr, lptr)                                                     \
    __builtin_amdgcn_global_load_lds(                                         \
        (const __attribute__((address_space(1))) void*)(gptr),                \
        (__attribute__((address_space(3))) void*)(lptr), 16, 0, 0)

// ---------------- Kernel 0: detect input dtype ------------------------------
__global__ void detect_k(const u32* __restrict__ xw, int* __restrict__ flag) {
    __shared__ int sh[256];
    int tid = threadIdx.x;
    u32 w = xw[tid * 64];
    int e = (w >> 7) & 0xFF;
    sh[tid] = (e >= 0x60 && e <= 0x90) ? 1 : 0;
    __syncthreads();
    for (int s = 128; s > 0; s >>= 1) {
        if (tid < s) sh[tid] += sh[tid + s];
        __syncthreads();
    }
    if (tid == 0) flag[0] = (sh[0] > 128) ? 1 : 0;   // 1 = bf16
}

// ---------------- Kernel 1: canonicalize x -> xb; also write out[...,0:512] -
__global__ void convx_k(const void* __restrict__ x, const int* __restrict__ flag,
                        u16* __restrict__ xb, void* __restrict__ out) {
    int i0 = (blockIdx.x * 256 + threadIdx.x) * 8;
    int row = i0 >> 9, col = i0 & 511;
    if (flag[0]) {
        uint4 v = *(const uint4*)((const u16*)x + i0);
        *(uint4*)&xb[i0] = v;
        *(uint4*)((u16*)out + (size_t)row * 1024 + col) = v;
    } else {
        const float* xf = (const float*)x;
        float4 f0 = *(const float4*)(xf + i0);
        float4 f1 = *(const float4*)(xf + i0 + 4);
        union { u16 us[8]; uint4 v; } pk;
        pk.us[0] = f2bf(f0.x); pk.us[1] = f2bf(f0.y);
        pk.us[2] = f2bf(f0.z); pk.us[3] = f2bf(f0.w);
        pk.us[4] = f2bf(f1.x); pk.us[5] = f2bf(f1.y);
        pk.us[6] = f2bf(f1.z); pk.us[7] = f2bf(f1.w);
        *(uint4*)&xb[i0] = pk.v;
        float* o = (float*)out + (size_t)row * 1024 + col;
        *(float4*)o = f0; *(float4*)(o + 4) = f1;
    }
}

// ---------------- Kernel 2: transpose + canonicalize weights ----------------
__global__ void convw_k(const void* __restrict__ Wq, const void* __restrict__ Wk,
                        const void* __restrict__ Wv, const int* __restrict__ flag,
                        u16* __restrict__ Wt) {
    int z = blockIdx.y;
    const void* W = (z == 0) ? Wq : ((z == 1) ? Wk : Wv);
    int flat = blockIdx.x * 256 + threadIdx.x;   // = n*512 + k
    int n = flat >> 9, k = flat & 511;
    u16 v = flag[0] ? ((const u16*)W)[k * 512 + n]
                    : f2bf(((const float*)W)[k * 512 + n]);
    Wt[z * 262144 + flat] = v;
}

// ---------------- Kernel 3: canonicalize biases -----------------------------
__global__ void convb_k(const void* __restrict__ bq, const void* __restrict__ bk,
                        const void* __restrict__ bv, const int* __restrict__ flag,
                        u16* __restrict__ bb) {
    int i = blockIdx.x * 256 + threadIdx.x;      // 0..1535
    int z = i >> 9, n = i & 511;
    const void* s = (z == 0) ? bq : ((z == 1) ? bk : bv);
    bb[i] = flag[0] ? ((const u16*)s)[n] : f2bf(((const float*)s)[n]);
}

// ---------------- Kernel 4: QKV projection GEMM -----------------------------
__global__ __launch_bounds__(256) void proj_k(
        const u16* __restrict__ x, const u16* __restrict__ Wt,
        const u16* __restrict__ bb,
        u16* __restrict__ Qo, u16* __restrict__ Ko, u16* __restrict__ Vt_out) {
    int z = blockIdx.z;
    const u16* Wz = Wt + z * 262144;                       // Wz[n][k]
    const u16* bias = bb + z * 512;
    int mBase = blockIdx.x * 128;
    int nBase = blockIdx.y * 128;

    __shared__ __attribute__((aligned(16))) u16 Xs[128 * 32];
    __shared__ __attribute__((aligned(16))) u16 Ws[128 * 32];

    int tid = threadIdx.x;
    int w = tid >> 6, lane = tid & 63, quad = lane >> 4, l16 = lane & 15;
    int wr = (w >> 1) * 64, wc = (w & 1) * 64;

    float4v acc[4][4] = {};

    for (int k0 = 0; k0 < 512; k0 += 32) {
        #pragma unroll
        for (int gg = 0; gg < 2; gg++) {                   // 1KB granules
            int g = w * 2 + gg;
            int row = g * 16 + (lane >> 2);
            int col8 = lane & 3;
            GLD16(&x [(size_t)(mBase + row) * 512 + k0 + col8 * 8], &Xs[g * 512]);
            GLD16(&Wz[(size_t)(nBase + row) * 512 + k0 + col8 * 8], &Ws[g * 512]);
        }
        __syncthreads();

        short8 a[4], b[4];
        #pragma unroll
        for (int mt = 0; mt < 4; mt++)
            a[mt] = *(const short8*)&Xs[(wr + mt * 16 + l16) * 32 + quad * 8];
        #pragma unroll
        for (int nt = 0; nt < 4; nt++)
            b[nt] = *(const short8*)&Ws[(wc + nt * 16 + l16) * 32 + quad * 8];
        #pragma unroll
        for (int mt = 0; mt < 4; mt++)
            #pragma unroll
            for (int nt = 0; nt < 4; nt++)
                acc[mt][nt] = mfma16(a[mt], b[nt], acc[mt][nt]);
        __syncthreads();
    }

    #pragma unroll
    for (int nt = 0; nt < 4; nt++) {
        int n = nBase + wc + nt * 16 + l16;
        float bval = bf2f(bias[n]);
        #pragma unroll
        for (int mt = 0; mt < 4; mt++) {
            int m0 = mBase + wr + mt * 16 + quad * 4;
            float4v v = acc[mt][nt];
            if (z == 2) {
                int bbi = m0 >> 11, tt = m0 & 2047;        // Vt[b][d=n][t]
                u16 t0 = f2bf(v[0] + bval), t1 = f2bf(v[1] + bval);
                u16 t2 = f2bf(v[2] + bval), t3 = f2bf(v[3] + bval);
                uint2 pk = make_uint2((u32)t0 | ((u32)t1 << 16), (u32)t2 | ((u32)t3 << 16));
                *(uint2*)&Vt_out[((size_t)bbi * 512 + n) * 2048 + tt] = pk;
            } else {
                u16* dst = (z == 0) ? Qo : Ko;
                #pragma unroll
                for (int r = 0; r < 4; r++)
                    dst[(size_t)(m0 + r) * 512 + n] = f2bf(v[r] + bval);
            }
        }
    }
}

// ---------------- Kernel 5: flash attention v6 ------------------------------
// grid 256 x 512 threads (8 waves = 2/SIMD). batch = blk&7 (XCD-local K/V),
// qt = blk>>3, Bq=64. S: wave (rg,kg) = 16 rows x 32 keys, Q in regs; softmax
// partials exchanged via LDS. PV: 8-way d-split (32 d per wave per half).
// K/V 32KB halves double-buffered via async global_load_lds one phase ahead.

#define LOADK(dst, kB, half)                                                  \
    { _Pragma("unroll")                                                       \
      for (int j = 0; j < 4; j++) {                                           \
        int row2 = 2 * (j * 8 + w);                                           \
        int row = row2 + (lane >> 5);                                         \
        int col8 = lane & 31;                                                 \
        GLD16(&Kb[(size_t)((kB) + row) * 512 + (half) * 256 +                 \
                  ((col8 ^ (row & 7)) << 3)], &dst[row2 * 256]);              \
      } }

#define LOADV(dst, kB, half)                                                  \
    { _Pragma("unroll")                                                       \
      for (int j = 0; j < 4; j++) {                                           \
        int blk8 = 8 * (j * 8 + w);                                           \
        int dl = blk8 + (lane >> 3);                                          \
        int col8 = lane & 7;                                                  \
        GLD16(&Vb[(size_t)((half) * 256 + dl) * 2048 + (kB) +                 \
                  ((col8 ^ (dl & 7)) << 3)], &dst[blk8 * 64]);                \
      } }

#define SSTEP(buf, h)                                                         \
    { _Pragma("unroll")                                                       \
      for (int kk = 0; kk < 8; kk++) {                                        \
        _Pragma("unroll")                                                     \
        for (int nt2 = 0; nt2 < 2; nt2++) {                                   \
          int key = kg * 32 + nt2 * 16 + l16;                                 \
          short8 bf = *(const short8*)&buf[key * 256 +                        \
                                           (((kk * 4 + quad) ^ sw) << 3)];    \
          accS[nt2] = mfma16(qf[(h) * 8 + kk], bf, accS[nt2]);                \
        } } }

#define PVSTEP(buf, accO)                                                     \
    { _Pragma("unroll")                                                       \
      for (int kk = 0; kk < 2; kk++) {                                        \
        _Pragma("unroll")                                                     \
        for (int dt = 0; dt < 2; dt++) {                                      \
          int drow = w * 32 + dt * 16 + l16;                                  \
          short8 bf = *(const short8*)&buf[drow * 64 +                        \
                                           (((kk * 4 + quad) ^ sw) << 3)];    \
          _Pragma("unroll")                                                   \
          for (int mt = 0; mt < 4; mt++)                                      \
            accO[dt][mt] = mfma16(pf[mt][kk], bf, accO[dt][mt]);              \
        } } }

__global__ __launch_bounds__(512, 2) void attn_k(
        const u16* __restrict__ Q, const u16* __restrict__ K,
        const u16* __restrict__ Vt, const int* __restrict__ flag,
        void* __restrict__ out) {
    int blk = blockIdx.x;
    int b = blk & 7, qt = blk >> 3;
    int q0 = qt * 64;
    int isbf = flag[0];

    __shared__ __attribute__((aligned(16))) u16 KV0[16384];   // 32 KB
    __shared__ __attribute__((aligned(16))) u16 KV1[16384];   // 32 KB
    __shared__ __attribute__((aligned(16))) u16 Ps[4096];     // P 64x64 (swizzled)
    __shared__ float pm_s[2][64];    // partial max per key-group
    __shared__ float ps_s[2][64];    // partial sum per key-group
    __shared__ float al_s[64];
    __shared__ float il_s[64];

    int tid = threadIdx.x;
    int w = tid >> 6, lane = tid & 63, quad = lane >> 4, l16 = lane & 15;
    int sw = l16 & 7;
    int rg = w >> 1, kg = w & 1;     // row-group (16 rows), key-group (32 keys)

    const u16* Qb = Q  + (size_t)b * 2048 * 512;
    const u16* Kb = K  + (size_t)b * 2048 * 512;
    const u16* Vb = Vt + (size_t)b * 512 * 2048;

    // prefetch tile0 K half0 -> KV0
    LOADK(KV0, 0, 0);

    // Q fragments: rows q0 + rg*16 + l16, full 512 d (64 VGPRs)
    short8 qf[16];
    {
        const u16* Qrow = &Qb[(size_t)(q0 + rg * 16 + l16) * 512];
        #pragma unroll
        for (int g = 0; g < 16; g++)
            qf[g] = *(const short8*)&Qrow[g * 32 + quad * 8];
    }

    float4v accA[2][4] = {};      // d = w*32 + dt*16 + l16        (half 0)
    float4v accB[2][4] = {};      // d = 256 + w*32 + dt*16 + l16  (half 1)
    float4v accS[2] = {};         // keys kg*32 + nt2*16 + l16, rows rg*16+quad*4+r
    short8 pf[4][2];
    float mrow[4] = {-1e30f, -1e30f, -1e30f, -1e30f};
    float lrow[4] = {0.f, 0.f, 0.f, 0.f};
    const float scale = 0.044194173824159216f;     // 1/sqrt(512)

    __syncthreads();

    for (int kt = 0; kt <= qt; kt++) {
        int kB = kt * 64;

        // ---- ph0: prefetch K half1 -> KV1; S += Q0.K0 from KV0 ----
        LOADK(KV1, kB, 1);
        SSTEP(KV0, 0);
        __syncthreads();

        // ---- ph1: prefetch V half0 -> KV0; S += Q1.K1; split softmax ----
        LOADV(KV0, kB, 0);
        SSTEP(KV1, 1);
        {
            int diag = (kt == qt);
            float pvv[2][4], alpha[4], mnewr[4];
            // partial max over this wave's 32 keys
            #pragma unroll
            for (int r = 0; r < 4; r++) {
                float mx = -1e30f;
                #pragma unroll
                for (int nt2 = 0; nt2 < 2; nt2++) {
                    float sv = accS[nt2][r] * scale;
                    if (diag && (kg * 32 + nt2 * 16 + l16 > rg * 16 + quad * 4 + r))
                        sv = -1e30f;
                    pvv[nt2][r] = sv;
                    mx = fmaxf(mx, sv);
                }
                mx = fmaxf(mx, __shfl_xor(mx, 1));
                mx = fmaxf(mx, __shfl_xor(mx, 2));
                mx = fmaxf(mx, __shfl_xor(mx, 4));
                mx = fmaxf(mx, __shfl_xor(mx, 8));
                if (l16 == 0) pm_s[kg][rg * 16 + quad * 4 + r] = mx;
            }
            __syncthreads();                       // B1: partial max visible
            #pragma unroll
            for (int r = 0; r < 4; r++) {
                int row = rg * 16 + quad * 4 + r;
                float mnew = fmaxf(mrow[r], fmaxf(pm_s[0][row], pm_s[1][row]));
                float a = __expf(mrow[r] - mnew);
                float sum = 0.f;
                #pragma unroll
                for (int nt2 = 0; nt2 < 2; nt2++) {
                    pvv[nt2][r] = __expf(pvv[nt2][r] - mnew);
                    sum += pvv[nt2][r];
                }
                sum += __shfl_xor(sum, 1);
                sum += __shfl_xor(sum, 2);
                sum += __shfl_xor(sum, 4);
                sum += __shfl_xor(sum, 8);
                if (l16 == 0) {
                    ps_s[kg][row] = sum;
                    if (kg == 0) al_s[row] = a;
                }
                mnewr[r] = mnew;
                alpha[r] = a;
            }
            // write P quarter (bf16, XOR-swizzled cols)
            #pragma unroll
            for (int nt2 = 0; nt2 < 2; nt2++)
                #pragma unroll
                for (int r = 0; r < 4; r++) {
                    int row = rg * 16 + quad * 4 + r;
                    int col = kg * 32 + nt2 * 16 + l16;
                    int cs = ((((col >> 3) ^ (row & 7)) << 3) | (col & 7));
                    Ps[row * 64 + cs] = f2bf(pvv[nt2][r]);
                }
            __syncthreads();                       // B2: sums + P visible
            #pragma unroll
            for (int r = 0; r < 4; r++) {
                int row = rg * 16 + quad * 4 + r;
                lrow[r] = lrow[r] * alpha[r] + ps_s[0][row] + ps_s[1][row];
                mrow[r] = mnewr[r];
            }
            accS[0] = (float4v){0.f, 0.f, 0.f, 0.f};
            accS[1] = (float4v){0.f, 0.f, 0.f, 0.f};
        }

        // ---- ph2: prefetch V half1 -> KV1; P-frags + rescale; O0 += P.V0 ----
        LOADV(KV1, kB, 1);
        {
            #pragma unroll
            for (int mt = 0; mt < 4; mt++)
                #pragma unroll
                for (int kk = 0; kk < 2; kk++)
                    pf[mt][kk] = *(const short8*)&Ps[(mt * 16 + l16) * 64 +
                                                     (((kk * 4 + quad) ^ sw) << 3)];
            float alf[4][4];
            #pragma unroll
            for (int mt = 0; mt < 4; mt++)
                #pragma unroll
                for (int r = 0; r < 4; r++)
                    alf[mt][r] = al_s[mt * 16 + quad * 4 + r];
            #pragma unroll
            for (int dt = 0; dt < 2; dt++)
                #pragma unroll
                for (int mt = 0; mt < 4; mt++)
                    #pragma unroll
                    for (int r = 0; r < 4; r++) {
                        accA[dt][mt][r] *= alf[mt][r];
                        accB[dt][mt][r] *= alf[mt][r];
                    }
        }
        PVSTEP(KV0, accA);
        __syncthreads();

        // ---- ph3: prefetch next K half0 -> KV0; O1 += P.V1 from KV1 ----
        if (kt < qt) LOADK(KV0, kB + 64, 0);
        PVSTEP(KV1, accB);
        __syncthreads();
    }

    // ---- epilogue: share 1/l, write out[..., 512:1024] ----
    if (kg == 0 && l16 == 0) {
        #pragma unroll
        for (int r = 0; r < 4; r++)
            il_s[rg * 16 + quad * 4 + r] = 1.0f / lrow[r];
    }
    __syncthreads();
    float invl[4][4];
    #pragma unroll
    for (int mt = 0; mt < 4; mt++)
        #pragma unroll
        for (int r = 0; r < 4; r++) invl[mt][r] = il_s[mt * 16 + quad * 4 + r];
    u16*   o16 = (u16*)out;
    float* o32 = (float*)out;
    #pragma unroll
    for (int dt = 0; dt < 2; dt++) {
        int dg0 = 512 + w * 32 + dt * 16 + l16;
        #pragma unroll
        for (int mt = 0; mt < 4; mt++)
            #pragma unroll
            for (int r = 0; r < 4; r++) {
                int rowg = q0 + mt * 16 + quad * 4 + r;
                size_t base = ((size_t)b * 2048 + rowg) * 1024;
                float v0 = accA[dt][mt][r] * invl[mt][r];
                float v1 = accB[dt][mt][r] * invl[mt][r];
                if (isbf) {
                    o16[base + dg0]       = f2bf(v0);
                    o16[base + dg0 + 256] = f2bf(v1);
                } else {
                    o32[base + dg0]       = v0;
                    o32[base + dg0 + 256] = v1;
                }
            }
    }
}

// ---------------- launcher --------------------------------------------------
extern "C" void kernel_launch(void* const* d_in, const int* in_sizes, int n_in,
                              void* d_out, int out_size, void* d_ws, size_t ws_size,
                              hipStream_t stream) {
    const void* x  = d_in[0];
    const void* Wq = d_in[1];
    const void* bq = d_in[2];
    const void* Wk = d_in[3];
    const void* bk = d_in[4];
    const void* Wv = d_in[5];
    const void* bv = d_in[6];

    u16* base = (u16*)d_ws;
    int* flag = (int*)base;                         // 16 B
    u16* Wt   = base + 8;                           // 3*512*512
    u16* bb   = Wt + 786432;                        // 1536 (pad 1544)
    u16* xb   = bb + 1544;                          // 8,388,608
    u16* Qw   = xb + 8388608;
    u16* Kw   = Qw + 8388608;
    u16* Vtw  = Kw + 8388608;                       // Vt[b][d][t]

    hipLaunchKernelGGL(detect_k, dim3(1), dim3(256), 0, stream, (const u32*)x, flag);
    hipLaunchKernelGGL(convx_k, dim3(4096), dim3(256), 0, stream, x, flag, xb, d_out);
    hipLaunchKernelGGL(convw_k, dim3(1024, 3), dim3(256), 0, stream, Wq, Wk, Wv, flag, Wt);
    hipLaunchKernelGGL(convb_k, dim3(6), dim3(256), 0, stream, bq, bk, bv, flag, bb);
    hipLaunchKernelGGL(proj_k, dim3(128, 4, 3), dim3(256), 0, stream, xb, Wt, bb, Qw, Kw, Vtw);
    hipLaunchKernelGGL(attn_k, dim3(256), dim3(512), 0, stream, Qw, Kw, Vtw, flag, d_out);
}